// Round 19
// baseline (261.858 us; speedup 1.0000x reference)
//
#include <hip/hip_runtime.h>
#include <cstddef>

typedef __bf16 bf16_t;
typedef __attribute__((ext_vector_type(8))) __bf16 bf16x8;
typedef __attribute__((ext_vector_type(4))) float f32x4;

#define BATCH 2
#define SEQ   2048
#define EMB   1024
#define ADIM  1024
#define NHEAD 16
#define HDIM  64
#define MROWS 4096

__device__ inline unsigned short f2bf(float f) {
    bf16_t b = (bf16_t)f;
    return __builtin_bit_cast(unsigned short, b);
}

// ---------------- fused prep: convert x (blocks 0..2047) + transpose W (2048..3071) ----------------
__global__ __launch_bounds__(256) void prep_kernel(
    const float* __restrict__ x,
    const float* __restrict__ Wq, const float* __restrict__ Wk,
    const float* __restrict__ Wv, const float* __restrict__ Wo,
    unsigned short* __restrict__ xb,
    unsigned short* __restrict__ Wt_qkv, unsigned short* __restrict__ Wt_o)
{
    __shared__ float tile[64][65];
    const int bx = blockIdx.x;
    if (bx < 2048) {
        const int i = bx * 256 + threadIdx.x;   // n8 = 524288 = 2048*256 exactly
        const float4* p = (const float4*)(x + (size_t)i * 8);
        float4 a = p[0], b = p[1];
        unsigned int w0 = f2bf(a.x) | ((unsigned)f2bf(a.y) << 16);
        unsigned int w1 = f2bf(a.z) | ((unsigned)f2bf(a.w) << 16);
        unsigned int w2 = f2bf(b.x) | ((unsigned)f2bf(b.y) << 16);
        unsigned int w3 = f2bf(b.z) | ((unsigned)f2bf(b.w) << 16);
        uint4 v = {w0, w1, w2, w3};
        *(uint4*)(xb + (size_t)i * 8) = v;
    } else {
        const int bz = bx - 2048;               // 0..1023
        const int m = bz >> 8;                  // 0..3
        const int rc = bz & 255;
        const float* W = (m == 0) ? Wq : (m == 1) ? Wk : (m == 2) ? Wv : Wo;
        unsigned short* dst = (m < 3) ? (Wt_qkv + (size_t)m * 1024 * 1024) : Wt_o;
        const int r0 = (rc >> 4) * 64, c0 = (rc & 15) * 64;
        const int t = threadIdx.x;
        const int r = t >> 2, c4 = (t & 3) * 16;
        #pragma unroll
        for (int j = 0; j < 16; j += 4) {
            float4 v = *(const float4*)(W + (size_t)(r0 + r) * 1024 + c0 + c4 + j);
            tile[r][c4 + j + 0] = v.x;
            tile[r][c4 + j + 1] = v.y;
            tile[r][c4 + j + 2] = v.z;
            tile[r][c4 + j + 3] = v.w;
        }
        __syncthreads();
        const int oc = t >> 2, ch = (t & 3) * 16;
        unsigned int ww[8];
        #pragma unroll
        for (int j = 0; j < 16; j += 2)
            ww[j >> 1] = f2bf(tile[ch + j][oc]) | ((unsigned)f2bf(tile[ch + j + 1][oc]) << 16);
        unsigned short* o = dst + (size_t)(c0 + oc) * 1024 + r0 + ch;
        *(uint4*)(o) = *(uint4*)&ww[0];
        *(uint4*)(o + 8) = *(uint4*)&ww[4];
    }
}

// ---------------- MFMA GEMM: 512 threads / 8 waves, 128x128 tile, BK=32 (R15-exact) ----------------
template<int EPI, int NBX, int NWG>
__global__ __launch_bounds__(512) void gemm_mfma_kernel(
    const unsigned short* __restrict__ A,
    const unsigned short* __restrict__ Bt,
    const float* __restrict__ b0, const float* __restrict__ b1, const float* __restrict__ b2,
    void* __restrict__ outp, unsigned short* __restrict__ vt)
{
    __shared__ __align__(16) unsigned short Asm[4096];
    __shared__ __align__(16) unsigned short Bsm[4096];
    const int tid = threadIdx.x, lane = tid & 63, w = tid >> 6;   // w 0..7
    const int wr = w >> 2, wc = w & 3;                            // 2 x 4 wave grid

    const int lin = blockIdx.x;
    const int wg = (lin & 7) * (NWG >> 3) + (lin >> 3);
    const int stripe = wg / (8 * NBX);
    const int rem = wg % (8 * NBX);
    const int bx = rem >> 3;
    const int by = stripe * 8 + (rem & 7);

    const int rowBase = by * 128, colBase = bx * 128;
    const int K = 1024;

    f32x4 acc[4][2];
    #pragma unroll
    for (int i = 0; i < 4; ++i)
        #pragma unroll
        for (int jx = 0; jx < 2; ++jx)
            acc[i][jx] = (f32x4){0.f, 0.f, 0.f, 0.f};

    const int mt_s = tid >> 6;
    const int cc_s = (tid & 63) >> 4;
    const int r16_s = tid & 15;

    for (int k0 = 0; k0 < K; k0 += 32) {
        __syncthreads();
        const unsigned short* ga = A + (size_t)(rowBase + mt_s * 16 + r16_s) * K + k0 + cc_s * 8;
        __builtin_amdgcn_global_load_lds(
            (const __attribute__((address_space(1))) unsigned int*)ga,
            (__attribute__((address_space(3))) unsigned int*)(Asm + (size_t)(w * 64) * 8),
            16, 0, 0);
        const unsigned short* gb = Bt + (size_t)(colBase + mt_s * 16 + r16_s) * K + k0 + cc_s * 8;
        __builtin_amdgcn_global_load_lds(
            (const __attribute__((address_space(1))) unsigned int*)gb,
            (__attribute__((address_space(3))) unsigned int*)(Bsm + (size_t)(w * 64) * 8),
            16, 0, 0);
        __syncthreads();

        bf16x8 af[4], bfr[2];
        #pragma unroll
        for (int mt = 0; mt < 4; ++mt)
            af[mt] = *(const bf16x8*)(Asm + (size_t)((wr * 4 + mt) * 64 + lane) * 8);
        #pragma unroll
        for (int nt = 0; nt < 2; ++nt)
            bfr[nt] = *(const bf16x8*)(Bsm + (size_t)((wc * 2 + nt) * 64 + lane) * 8);
        #pragma unroll
        for (int mt = 0; mt < 4; ++mt)
            #pragma unroll
            for (int nt = 0; nt < 2; ++nt)
                acc[mt][nt] = __builtin_amdgcn_mfma_f32_16x16x32_bf16(af[mt], bfr[nt], acc[mt][nt], 0, 0, 0);
    }

    const int g = lane >> 4, r16 = lane & 15;
    const int seg = colBase >> 10;
    const float* bias = (seg == 0) ? b0 : (seg == 1) ? b1 : b2;

    if (EPI == 0) {
        unsigned short* qkv = (unsigned short*)outp;
        #pragma unroll
        for (int mt = 0; mt < 4; ++mt) {
            const int row0 = rowBase + wr * 64 + mt * 16 + 4 * g;
            #pragma unroll
            for (int nt = 0; nt < 2; ++nt) {
                const int col = colBase + wc * 32 + nt * 16 + r16;
                const float bb = bias[col & 1023];
                if (seg < 2) {
                    #pragma unroll
                    for (int rr = 0; rr < 4; ++rr)
                        qkv[(size_t)(row0 + rr) * 3072 + col] = f2bf(acc[mt][nt][rr] + bb);
                } else {
                    unsigned int p0 = f2bf(acc[mt][nt][0] + bb) | ((unsigned)f2bf(acc[mt][nt][1] + bb) << 16);
                    unsigned int p1 = f2bf(acc[mt][nt][2] + bb) | ((unsigned)f2bf(acc[mt][nt][3] + bb) << 16);
                    uint2 pv = {p0, p1};
                    *(uint2*)(vt + (size_t)(col - 2048) * 4096 + row0) = pv;
                }
            }
        }
    } else {
        float* out = (float*)outp;
        #pragma unroll
        for (int mt = 0; mt < 4; ++mt) {
            const int row0 = rowBase + wr * 64 + mt * 16 + 4 * g;
            #pragma unroll
            for (int nt = 0; nt < 2; ++nt) {
                const int col = colBase + wc * 32 + nt * 16 + r16;
                const float bb = bias[col];
                #pragma unroll
                for (int rr = 0; rr < 4; ++rr)
                    out[(size_t)(row0 + rr) * 1024 + col] = acc[mt][nt][rr] + bb;
            }
        }
    }
}

// ---------------- MFMA attention (R18) + zero-fill hoisted to front ----------------
__global__ __launch_bounds__(256, 4) void attn_mfma_kernel(
    const unsigned short* __restrict__ qkv,  // [4096][3072] bf16: Q 0..1023, K 1024..2047
    const unsigned short* __restrict__ vt,   // [1024][4096] bf16: Vt[d][b*S+s]
    float* __restrict__ attn,                // [32][2048][2048] fp32
    unsigned short* __restrict__ ctx)        // [4096][1024] bf16
{
    __shared__ __align__(16) unsigned short Ksm[2][4096];
    __shared__ __align__(16) unsigned short Vsm[2][4096];
    __shared__ __align__(16) unsigned short Psm[4][1024];

    const int j = blockIdx.x;
    const int xcd = j & 7, slot = j >> 3;
    const int bh = xcd + 8 * (slot & 3);
    const int s4 = slot >> 2;
    const int qt = 8 * (s4 >> 3) + (((s4 & 7) + 2 * (s4 >> 3)) & 7);
    const int b = bh >> 4, h = bh & 15;
    const int tid = threadIdx.x, lane = tid & 63, w = tid >> 6;
    const int g = lane >> 4, r16 = lane & 15;
    const int qrow0 = qt * 64 + w * 16;
    const int q = qrow0 + r16;            // this lane's q-row (swapped layout)

    bf16x8 qf[2];
    #pragma unroll
    for (int k2 = 0; k2 < 2; ++k2)
        qf[k2] = *(const bf16x8*)(qkv + (size_t)(b * SEQ + qrow0 + r16) * 3072 + h * 64 + k2 * 32 + g * 8);

    // ---- zero-fill strictly-above-diagonal region FIRST: stores retire under compute ----
    {
        const int colStart = 64 * (qt + 1);
        const int Wc = SEQ - colStart;
        if (Wc > 0) {
            const int w4 = Wc >> 2;
            for (int c = tid; c < 64 * w4; c += 256) {
                const int row = qt * 64 + c / w4;
                const int col = colStart + (c % w4) * 4;
                *(float4*)(attn + ((size_t)bh * SEQ + row) * SEQ + col) = make_float4(0.f, 0.f, 0.f, 0.f);
            }
        }
    }

    const int sr = tid >> 2;
    const int sbc = (tid & 3) * 32;
    const int swz = (sr & 7) << 4;
    char* Kb = (char*)Ksm;
    char* Vb = (char*)Vsm;

    float rsum1 = 0.f;

    // ---- phase 1: rowsums; 4-slot K ring over {Ksm,Vsm}, 2 tiles per barrier ----
    {
        const char* gk0 = (const char*)(qkv + (size_t)(b * SEQ + sr) * 3072 + 1024 + h * 64);
        uint4 p0 = *(const uint4*)(gk0 + sbc);
        uint4 p1 = *(const uint4*)(gk0 + sbc + 16);
        *(uint4*)(Kb + ((sr * 128 + sbc) ^ swz)) = p0;
        *(uint4*)(Kb + ((sr * 128 + sbc + 16) ^ swz)) = p1;
        if (qt >= 1) {
            const char* gk1 = (const char*)(qkv + (size_t)(b * SEQ + 64 + sr) * 3072 + 1024 + h * 64);
            uint4 q0 = *(const uint4*)(gk1 + sbc);
            uint4 q1 = *(const uint4*)(gk1 + sbc + 16);
            *(uint4*)(Kb + 8192 + ((sr * 128 + sbc) ^ swz)) = q0;
            *(uint4*)(Kb + 8192 + ((sr * 128 + sbc + 16) ^ swz)) = q1;
        }
    }
    __syncthreads();
    for (int t0 = 0; t0 <= qt; t0 += 2) {
        uint4 a0, a1, c0, c1;
        const bool pf2 = (t0 + 2 <= qt), pf3 = (t0 + 3 <= qt);
        if (pf2) {
            const char* gk = (const char*)(qkv + (size_t)(b * SEQ + (t0 + 2) * 64 + sr) * 3072 + 1024 + h * 64);
            a0 = *(const uint4*)(gk + sbc);
            a1 = *(const uint4*)(gk + sbc + 16);
        }
        if (pf3) {
            const char* gk = (const char*)(qkv + (size_t)(b * SEQ + (t0 + 3) * 64 + sr) * 3072 + 1024 + h * 64);
            c0 = *(const uint4*)(gk + sbc);
            c1 = *(const uint4*)(gk + sbc + 16);
        }
        #pragma unroll
        for (int sub = 0; sub < 2; ++sub) {
            const int kt = t0 + sub;
            if (kt <= qt) {
                const char* Kc = ((kt & 2) ? Vb : Kb) + (kt & 1) * 8192;
                #pragma unroll
                for (int nt = 0; nt < 4; ++nt) {
                    f32x4 s = {0.f, 0.f, 0.f, 0.f};
                    const int krow = nt * 16 + r16;
                    #pragma unroll
                    for (int k2 = 0; k2 < 2; ++k2) {
                        bf16x8 kf = *(const bf16x8*)(Kc + ((krow * 128 + k2 * 64 + g * 16) ^ ((krow & 7) << 4)));
                        s = __builtin_amdgcn_mfma_f32_16x16x32_bf16(kf, qf[k2], s, 0, 0, 0);  // swapped
                    }
                    const int k0i = kt * 64 + nt * 16 + 4 * g;
                    #pragma unroll
                    for (int rr = 0; rr < 4; ++rr)
                        if (k0i + rr <= q) rsum1 += __expf(s[rr] * 0.125f);
                }
            }
        }
        if (pf2) {
            char* dstp = (((t0 + 2) & 2) ? Vb : Kb) + ((t0 + 2) & 1) * 8192;
            *(uint4*)(dstp + ((sr * 128 + sbc) ^ swz)) = a0;
            *(uint4*)(dstp + ((sr * 128 + sbc + 16) ^ swz)) = a1;
        }
        if (pf3) {
            char* dstp = (((t0 + 3) & 2) ? Vb : Kb) + ((t0 + 3) & 1) * 8192;
            *(uint4*)(dstp + ((sr * 128 + sbc) ^ swz)) = c0;
            *(uint4*)(dstp + ((sr * 128 + sbc + 16) ^ swz)) = c1;
        }
        __syncthreads();
    }
    float inv;
    {
        float v = rsum1;
        v += __shfl_xor(v, 16, 64);
        v += __shfl_xor(v, 32, 64);
        inv = 1.0f / v;
    }

    f32x4 cacc[4];
    #pragma unroll
    for (int nt = 0; nt < 4; ++nt) cacc[nt] = (f32x4){0.f, 0.f, 0.f, 0.f};

    // ---- phase 2: swapped QK^T -> float4 attn stores + uint2 Psm writes; PV unchanged ----
    {
        const char* gk = (const char*)(qkv + (size_t)(b * SEQ + sr) * 3072 + 1024 + h * 64);
        uint4 a0 = *(const uint4*)(gk + sbc);
        uint4 a1 = *(const uint4*)(gk + sbc + 16);
        const char* gv = (const char*)(vt + (size_t)(h * 64 + sr) * 4096 + b * SEQ);
        uint4 v0 = *(const uint4*)(gv + sbc);
        uint4 v1 = *(const uint4*)(gv + sbc + 16);
        *(uint4*)(Kb + ((sr * 128 + sbc) ^ swz)) = a0;
        *(uint4*)(Kb + ((sr * 128 + sbc + 16) ^ swz)) = a1;
        *(uint4*)(Vb + ((sr * 128 + sbc) ^ swz)) = v0;
        *(uint4*)(Vb + ((sr * 128 + sbc + 16) ^ swz)) = v1;
    }
    __syncthreads();
    for (int kt = 0; kt <= qt; ++kt) {
        const int cur = kt & 1;
        const int kbase = kt * 64;
        uint4 a0, a1, v0, v1;
        if (kt < qt) {
            const char* gk = (const char*)(qkv + (size_t)(b * SEQ + kbase + 64 + sr) * 3072 + 1024 + h * 64);
            a0 = *(const uint4*)(gk + sbc);
            a1 = *(const uint4*)(gk + sbc + 16);
            const char* gv = (const char*)(vt + (size_t)(h * 64 + sr) * 4096 + b * SEQ + kbase + 64);
            v0 = *(const uint4*)(gv + sbc);
            v1 = *(const uint4*)(gv + sbc + 16);
        }
        const char* Kc = Kb + cur * 8192;
        const char* Vc = Vb + cur * 8192;

        #pragma unroll
        for (int nt = 0; nt < 4; ++nt) {
            f32x4 s = {0.f, 0.f, 0.f, 0.f};
            const int krow = nt * 16 + r16;
            #pragma unroll
            for (int k2 = 0; k2 < 2; ++k2) {
                bf16x8 kf = *(const bf16x8*)(Kc + ((krow * 128 + k2 * 64 + g * 16) ^ ((krow & 7) << 4)));
                s = __builtin_amdgcn_mfma_f32_16x16x32_bf16(kf, qf[k2], s, 0, 0, 0);  // swapped
            }
            const int k0i = kbase + nt * 16 + 4 * g;
            float4 p4;
            p4.x = (k0i + 0 <= q) ? __expf(s[0] * 0.125f) * inv : 0.0f;
            p4.y = (k0i + 1 <= q) ? __expf(s[1] * 0.125f) * inv : 0.0f;
            p4.z = (k0i + 2 <= q) ? __expf(s[2] * 0.125f) * inv : 0.0f;
            p4.w = (k0i + 3 <= q) ? __expf(s[3] * 0.125f) * inv : 0.0f;
            *(float4*)(attn + ((size_t)bh * SEQ + q) * SEQ + k0i) = p4;
            uint2 pw;
            pw.x = f2bf(p4.x) | ((unsigned)f2bf(p4.y) << 16);
            pw.y = f2bf(p4.z) | ((unsigned)f2bf(p4.w) << 16);
            *(uint2*)((char*)(Psm[w]) + ((r16 * 128 + nt * 32 + g * 8) ^ ((r16 & 7) << 4))) = pw;
        }
        // PV: A = P (per-wave LDS, layout unchanged), B = V
        bf16x8 pf[2];
        #pragma unroll
        for (int k2 = 0; k2 < 2; ++k2)
            pf[k2] = *(const bf16x8*)((char*)(Psm[w]) + ((r16 * 128 + k2 * 64 + g * 16) ^ ((r16 & 7) << 4)));
        #pragma unroll
        for (int nt = 0; nt < 4; ++nt) {
            const int vrow = nt * 16 + r16;
            #pragma unroll
            for (int k2 = 0; k2 < 2; ++k2) {
                bf16x8 vf = *(const bf16x8*)(Vc + ((vrow * 128 + k2 * 64 + g * 16) ^ ((vrow & 7) << 4)));
                cacc[nt] = __builtin_amdgcn_mfma_f32_16x16x32_bf16(pf[k2], vf, cacc[nt], 0, 0, 0);
            }
        }
        if (kt < qt) {
            char* Kn = Kb + (cur ^ 1) * 8192;
            char* Vn = Vb + (cur ^ 1) * 8192;
            *(uint4*)(Kn + ((sr * 128 + sbc) ^ swz)) = a0;
            *(uint4*)(Kn + ((sr * 128 + sbc + 16) ^ swz)) = a1;
            *(uint4*)(Vn + ((sr * 128 + sbc) ^ swz)) = v0;
            *(uint4*)(Vn + ((sr * 128 + sbc + 16) ^ swz)) = v1;
        }
        __syncthreads();
    }

    // ctx write (PV layout unchanged)
    #pragma unroll
    for (int nt = 0; nt < 4; ++nt)
        #pragma unroll
        for (int rr = 0; rr < 4; ++rr) {
            const int qq = qrow0 + 4 * g + rr;
            ctx[(size_t)(b * SEQ + qq) * 1024 + h * 64 + nt * 16 + r16] = f2bf(cacc[nt][rr]);
        }
}

extern "C" void kernel_launch(void* const* d_in, const int* in_sizes, int n_in,
                              void* d_out, int out_size, void* d_ws, size_t ws_size,
                              hipStream_t stream)
{
    const float* x  = (const float*)d_in[0];
    const float* Wq = (const float*)d_in[1];
    const float* bq = (const float*)d_in[2];
    const float* Wk = (const float*)d_in[3];
    const float* bk = (const float*)d_in[4];
    const float* Wv = (const float*)d_in[5];
    const float* bv = (const float*)d_in[6];
    const float* Wo = (const float*)d_in[7];
    const float* bo = (const float*)d_in[8];

    float* out  = (float*)d_out;
    float* attn = out + (size_t)BATCH * SEQ * EMB;

    unsigned short* xb     = (unsigned short*)d_ws;
    unsigned short* wt_qkv = xb + (size_t)MROWS * 1024;
    unsigned short* wt_o   = wt_qkv + (size_t)3072 * 1024;
    unsigned short* qkvb   = wt_o + (size_t)1024 * 1024;
    unsigned short* vtb    = qkvb + (size_t)MROWS * 3072;
    unsigned short* ctxb   = vtb + (size_t)1024 * MROWS;

    prep_kernel<<<3072, 256, 0, stream>>>(x, Wq, Wk, Wv, Wo, xb, wt_qkv, wt_o);

    gemm_mfma_kernel<0, 24, 768><<<768, 512, 0, stream>>>(xb, wt_qkv, bq, bk, bv, qkvb, vtb);

    attn_mfma_kernel<<<1024, 256, 0, stream>>>(qkvb, vtb, attn, ctxb);

    gemm_mfma_kernel<1, 8, 256><<<256, 512, 0, stream>>>(ctxb, wt_o, bo, bo, bo, out, nullptr);
}

// Round 20
// 234.129 us; speedup vs baseline: 1.1184x; 1.1184x over previous
//
#include <hip/hip_runtime.h>
#include <cstddef>

typedef __bf16 bf16_t;
typedef __attribute__((ext_vector_type(8))) __bf16 bf16x8;
typedef __attribute__((ext_vector_type(4))) float f32x4;

#define BATCH 2
#define SEQ   2048
#define EMB   1024
#define ADIM  1024
#define NHEAD 16
#define HDIM  64
#define MROWS 4096

__device__ inline unsigned short f2bf(float f) {
    bf16_t b = (bf16_t)f;
    return __builtin_bit_cast(unsigned short, b);
}

// ---------------- fused prep: convert x (blocks 0..2047) + transpose W (2048..3071) ----------------
__global__ __launch_bounds__(256) void prep_kernel(
    const float* __restrict__ x,
    const float* __restrict__ Wq, const float* __restrict__ Wk,
    const float* __restrict__ Wv, const float* __restrict__ Wo,
    unsigned short* __restrict__ xb,
    unsigned short* __restrict__ Wt_qkv, unsigned short* __restrict__ Wt_o)
{
    __shared__ float tile[64][65];
    const int bx = blockIdx.x;
    if (bx < 2048) {
        const int i = bx * 256 + threadIdx.x;   // n8 = 524288 = 2048*256 exactly
        const float4* p = (const float4*)(x + (size_t)i * 8);
        float4 a = p[0], b = p[1];
        unsigned int w0 = f2bf(a.x) | ((unsigned)f2bf(a.y) << 16);
        unsigned int w1 = f2bf(a.z) | ((unsigned)f2bf(a.w) << 16);
        unsigned int w2 = f2bf(b.x) | ((unsigned)f2bf(b.y) << 16);
        unsigned int w3 = f2bf(b.z) | ((unsigned)f2bf(b.w) << 16);
        uint4 v = {w0, w1, w2, w3};
        *(uint4*)(xb + (size_t)i * 8) = v;
    } else {
        const int bz = bx - 2048;               // 0..1023
        const int m = bz >> 8;                  // 0..3
        const int rc = bz & 255;
        const float* W = (m == 0) ? Wq : (m == 1) ? Wk : (m == 2) ? Wv : Wo;
        unsigned short* dst = (m < 3) ? (Wt_qkv + (size_t)m * 1024 * 1024) : Wt_o;
        const int r0 = (rc >> 4) * 64, c0 = (rc & 15) * 64;
        const int t = threadIdx.x;
        const int r = t >> 2, c4 = (t & 3) * 16;
        #pragma unroll
        for (int j = 0; j < 16; j += 4) {
            float4 v = *(const float4*)(W + (size_t)(r0 + r) * 1024 + c0 + c4 + j);
            tile[r][c4 + j + 0] = v.x;
            tile[r][c4 + j + 1] = v.y;
            tile[r][c4 + j + 2] = v.z;
            tile[r][c4 + j + 3] = v.w;
        }
        __syncthreads();
        const int oc = t >> 2, ch = (t & 3) * 16;
        unsigned int ww[8];
        #pragma unroll
        for (int j = 0; j < 16; j += 2)
            ww[j >> 1] = f2bf(tile[ch + j][oc]) | ((unsigned)f2bf(tile[ch + j + 1][oc]) << 16);
        unsigned short* o = dst + (size_t)(c0 + oc) * 1024 + r0 + ch;
        *(uint4*)(o) = *(uint4*)&ww[0];
        *(uint4*)(o + 8) = *(uint4*)&ww[4];
    }
}

// ---------------- MFMA GEMM: 512 threads / 8 waves, 128x128 tile, BK=32 (R15-exact) ----------------
template<int EPI, int NBX, int NWG>
__global__ __launch_bounds__(512) void gemm_mfma_kernel(
    const unsigned short* __restrict__ A,
    const unsigned short* __restrict__ Bt,
    const float* __restrict__ b0, const float* __restrict__ b1, const float* __restrict__ b2,
    void* __restrict__ outp, unsigned short* __restrict__ vt)
{
    __shared__ __align__(16) unsigned short Asm[4096];
    __shared__ __align__(16) unsigned short Bsm[4096];
    const int tid = threadIdx.x, lane = tid & 63, w = tid >> 6;   // w 0..7
    const int wr = w >> 2, wc = w & 3;                            // 2 x 4 wave grid

    const int lin = blockIdx.x;
    const int wg = (lin & 7) * (NWG >> 3) + (lin >> 3);
    const int stripe = wg / (8 * NBX);
    const int rem = wg % (8 * NBX);
    const int bx = rem >> 3;
    const int by = stripe * 8 + (rem & 7);

    const int rowBase = by * 128, colBase = bx * 128;
    const int K = 1024;

    f32x4 acc[4][2];
    #pragma unroll
    for (int i = 0; i < 4; ++i)
        #pragma unroll
        for (int jx = 0; jx < 2; ++jx)
            acc[i][jx] = (f32x4){0.f, 0.f, 0.f, 0.f};

    const int mt_s = tid >> 6;
    const int cc_s = (tid & 63) >> 4;
    const int r16_s = tid & 15;

    for (int k0 = 0; k0 < K; k0 += 32) {
        __syncthreads();
        const unsigned short* ga = A + (size_t)(rowBase + mt_s * 16 + r16_s) * K + k0 + cc_s * 8;
        __builtin_amdgcn_global_load_lds(
            (const __attribute__((address_space(1))) unsigned int*)ga,
            (__attribute__((address_space(3))) unsigned int*)(Asm + (size_t)(w * 64) * 8),
            16, 0, 0);
        const unsigned short* gb = Bt + (size_t)(colBase + mt_s * 16 + r16_s) * K + k0 + cc_s * 8;
        __builtin_amdgcn_global_load_lds(
            (const __attribute__((address_space(1))) unsigned int*)gb,
            (__attribute__((address_space(3))) unsigned int*)(Bsm + (size_t)(w * 64) * 8),
            16, 0, 0);
        __syncthreads();

        bf16x8 af[4], bfr[2];
        #pragma unroll
        for (int mt = 0; mt < 4; ++mt)
            af[mt] = *(const bf16x8*)(Asm + (size_t)((wr * 4 + mt) * 64 + lane) * 8);
        #pragma unroll
        for (int nt = 0; nt < 2; ++nt)
            bfr[nt] = *(const bf16x8*)(Bsm + (size_t)((wc * 2 + nt) * 64 + lane) * 8);
        #pragma unroll
        for (int mt = 0; mt < 4; ++mt)
            #pragma unroll
            for (int nt = 0; nt < 2; ++nt)
                acc[mt][nt] = __builtin_amdgcn_mfma_f32_16x16x32_bf16(af[mt], bfr[nt], acc[mt][nt], 0, 0, 0);
    }

    const int g = lane >> 4, r16 = lane & 15;
    const int seg = colBase >> 10;
    const float* bias = (seg == 0) ? b0 : (seg == 1) ? b1 : b2;

    if (EPI == 0) {
        unsigned short* qkv = (unsigned short*)outp;
        #pragma unroll
        for (int mt = 0; mt < 4; ++mt) {
            const int row0 = rowBase + wr * 64 + mt * 16 + 4 * g;
            #pragma unroll
            for (int nt = 0; nt < 2; ++nt) {
                const int col = colBase + wc * 32 + nt * 16 + r16;
                const float bb = bias[col & 1023];
                if (seg < 2) {
                    #pragma unroll
                    for (int rr = 0; rr < 4; ++rr)
                        qkv[(size_t)(row0 + rr) * 3072 + col] = f2bf(acc[mt][nt][rr] + bb);
                } else {
                    unsigned int p0 = f2bf(acc[mt][nt][0] + bb) | ((unsigned)f2bf(acc[mt][nt][1] + bb) << 16);
                    unsigned int p1 = f2bf(acc[mt][nt][2] + bb) | ((unsigned)f2bf(acc[mt][nt][3] + bb) << 16);
                    uint2 pv = {p0, p1};
                    *(uint2*)(vt + (size_t)(col - 2048) * 4096 + row0) = pv;
                }
            }
        }
    } else {
        float* out = (float*)outp;
        #pragma unroll
        for (int mt = 0; mt < 4; ++mt) {
            const int row0 = rowBase + wr * 64 + mt * 16 + 4 * g;
            #pragma unroll
            for (int nt = 0; nt < 2; ++nt) {
                const int col = colBase + wc * 32 + nt * 16 + r16;
                const float bb = bias[col];
                #pragma unroll
                for (int rr = 0; rr < 4; ++rr)
                    out[(size_t)(row0 + rr) * 1024 + col] = acc[mt][nt][rr] + bb;
            }
        }
    }
}

// ---------------- MFMA attention (R14-exact): swapped QK^T, ring phase 1, trailing zero-fill ----------------
__global__ __launch_bounds__(256, 4) void attn_mfma_kernel(
    const unsigned short* __restrict__ qkv,  // [4096][3072] bf16: Q 0..1023, K 1024..2047
    const unsigned short* __restrict__ vt,   // [1024][4096] bf16: Vt[d][b*S+s]
    float* __restrict__ attn,                // [32][2048][2048] fp32
    unsigned short* __restrict__ ctx)        // [4096][1024] bf16
{
    __shared__ __align__(16) unsigned short Ksm[2][4096];
    __shared__ __align__(16) unsigned short Vsm[2][4096];
    __shared__ __align__(16) unsigned short Psm[4][1024];

    const int j = blockIdx.x;
    const int xcd = j & 7, slot = j >> 3;
    const int bh = xcd + 8 * (slot & 3);
    const int s4 = slot >> 2;
    const int qt = 8 * (s4 >> 3) + (((s4 & 7) + 2 * (s4 >> 3)) & 7);
    const int b = bh >> 4, h = bh & 15;
    const int tid = threadIdx.x, lane = tid & 63, w = tid >> 6;
    const int g = lane >> 4, r16 = lane & 15;
    const int qrow0 = qt * 64 + w * 16;
    const int q = qrow0 + r16;            // this lane's q-row (swapped layout)

    bf16x8 qf[2];
    #pragma unroll
    for (int k2 = 0; k2 < 2; ++k2)
        qf[k2] = *(const bf16x8*)(qkv + (size_t)(b * SEQ + qrow0 + r16) * 3072 + h * 64 + k2 * 32 + g * 8);

    const int sr = tid >> 2;
    const int sbc = (tid & 3) * 32;
    const int swz = (sr & 7) << 4;
    char* Kb = (char*)Ksm;
    char* Vb = (char*)Vsm;

    float rsum1 = 0.f;

    // ---- phase 1: rowsums; 4-slot K ring over {Ksm,Vsm}, 2 tiles per barrier ----
    {
        const char* gk0 = (const char*)(qkv + (size_t)(b * SEQ + sr) * 3072 + 1024 + h * 64);
        uint4 p0 = *(const uint4*)(gk0 + sbc);
        uint4 p1 = *(const uint4*)(gk0 + sbc + 16);
        *(uint4*)(Kb + ((sr * 128 + sbc) ^ swz)) = p0;
        *(uint4*)(Kb + ((sr * 128 + sbc + 16) ^ swz)) = p1;
        if (qt >= 1) {
            const char* gk1 = (const char*)(qkv + (size_t)(b * SEQ + 64 + sr) * 3072 + 1024 + h * 64);
            uint4 q0 = *(const uint4*)(gk1 + sbc);
            uint4 q1 = *(const uint4*)(gk1 + sbc + 16);
            *(uint4*)(Kb + 8192 + ((sr * 128 + sbc) ^ swz)) = q0;
            *(uint4*)(Kb + 8192 + ((sr * 128 + sbc + 16) ^ swz)) = q1;
        }
    }
    __syncthreads();
    for (int t0 = 0; t0 <= qt; t0 += 2) {
        uint4 a0, a1, c0, c1;
        const bool pf2 = (t0 + 2 <= qt), pf3 = (t0 + 3 <= qt);
        if (pf2) {
            const char* gk = (const char*)(qkv + (size_t)(b * SEQ + (t0 + 2) * 64 + sr) * 3072 + 1024 + h * 64);
            a0 = *(const uint4*)(gk + sbc);
            a1 = *(const uint4*)(gk + sbc + 16);
        }
        if (pf3) {
            const char* gk = (const char*)(qkv + (size_t)(b * SEQ + (t0 + 3) * 64 + sr) * 3072 + 1024 + h * 64);
            c0 = *(const uint4*)(gk + sbc);
            c1 = *(const uint4*)(gk + sbc + 16);
        }
        #pragma unroll
        for (int sub = 0; sub < 2; ++sub) {
            const int kt = t0 + sub;
            if (kt <= qt) {
                const char* Kc = ((kt & 2) ? Vb : Kb) + (kt & 1) * 8192;
                #pragma unroll
                for (int nt = 0; nt < 4; ++nt) {
                    f32x4 s = {0.f, 0.f, 0.f, 0.f};
                    const int krow = nt * 16 + r16;
                    #pragma unroll
                    for (int k2 = 0; k2 < 2; ++k2) {
                        bf16x8 kf = *(const bf16x8*)(Kc + ((krow * 128 + k2 * 64 + g * 16) ^ ((krow & 7) << 4)));
                        s = __builtin_amdgcn_mfma_f32_16x16x32_bf16(kf, qf[k2], s, 0, 0, 0);  // swapped
                    }
                    const int k0i = kt * 64 + nt * 16 + 4 * g;
                    #pragma unroll
                    for (int rr = 0; rr < 4; ++rr)
                        if (k0i + rr <= q) rsum1 += __expf(s[rr] * 0.125f);
                }
            }
        }
        if (pf2) {
            char* dstp = (((t0 + 2) & 2) ? Vb : Kb) + ((t0 + 2) & 1) * 8192;
            *(uint4*)(dstp + ((sr * 128 + sbc) ^ swz)) = a0;
            *(uint4*)(dstp + ((sr * 128 + sbc + 16) ^ swz)) = a1;
        }
        if (pf3) {
            char* dstp = (((t0 + 3) & 2) ? Vb : Kb) + ((t0 + 3) & 1) * 8192;
            *(uint4*)(dstp + ((sr * 128 + sbc) ^ swz)) = c0;
            *(uint4*)(dstp + ((sr * 128 + sbc + 16) ^ swz)) = c1;
        }
        __syncthreads();
    }
    float inv;
    {
        float v = rsum1;
        v += __shfl_xor(v, 16, 64);
        v += __shfl_xor(v, 32, 64);
        inv = 1.0f / v;
    }

    f32x4 cacc[4];
    #pragma unroll
    for (int nt = 0; nt < 4; ++nt) cacc[nt] = (f32x4){0.f, 0.f, 0.f, 0.f};

    // ---- phase 2: swapped QK^T -> float4 attn stores + uint2 Psm writes; PV unchanged ----
    {
        const char* gk = (const char*)(qkv + (size_t)(b * SEQ + sr) * 3072 + 1024 + h * 64);
        uint4 a0 = *(const uint4*)(gk + sbc);
        uint4 a1 = *(const uint4*)(gk + sbc + 16);
        const char* gv = (const char*)(vt + (size_t)(h * 64 + sr) * 4096 + b * SEQ);
        uint4 v0 = *(const uint4*)(gv + sbc);
        uint4 v1 = *(const uint4*)(gv + sbc + 16);
        *(uint4*)(Kb + ((sr * 128 + sbc) ^ swz)) = a0;
        *(uint4*)(Kb + ((sr * 128 + sbc + 16) ^ swz)) = a1;
        *(uint4*)(Vb + ((sr * 128 + sbc) ^ swz)) = v0;
        *(uint4*)(Vb + ((sr * 128 + sbc + 16) ^ swz)) = v1;
    }
    __syncthreads();
    for (int kt = 0; kt <= qt; ++kt) {
        const int cur = kt & 1;
        const int kbase = kt * 64;
        uint4 a0, a1, v0, v1;
        if (kt < qt) {
            const char* gk = (const char*)(qkv + (size_t)(b * SEQ + kbase + 64 + sr) * 3072 + 1024 + h * 64);
            a0 = *(const uint4*)(gk + sbc);
            a1 = *(const uint4*)(gk + sbc + 16);
            const char* gv = (const char*)(vt + (size_t)(h * 64 + sr) * 4096 + b * SEQ + kbase + 64);
            v0 = *(const uint4*)(gv + sbc);
            v1 = *(const uint4*)(gv + sbc + 16);
        }
        const char* Kc = Kb + cur * 8192;
        const char* Vc = Vb + cur * 8192;

        #pragma unroll
        for (int nt = 0; nt < 4; ++nt) {
            f32x4 s = {0.f, 0.f, 0.f, 0.f};
            const int krow = nt * 16 + r16;
            #pragma unroll
            for (int k2 = 0; k2 < 2; ++k2) {
                bf16x8 kf = *(const bf16x8*)(Kc + ((krow * 128 + k2 * 64 + g * 16) ^ ((krow & 7) << 4)));
                s = __builtin_amdgcn_mfma_f32_16x16x32_bf16(kf, qf[k2], s, 0, 0, 0);  // swapped
            }
            const int k0i = kbase + nt * 16 + 4 * g;
            float4 p4;
            p4.x = (k0i + 0 <= q) ? __expf(s[0] * 0.125f) * inv : 0.0f;
            p4.y = (k0i + 1 <= q) ? __expf(s[1] * 0.125f) * inv : 0.0f;
            p4.z = (k0i + 2 <= q) ? __expf(s[2] * 0.125f) * inv : 0.0f;
            p4.w = (k0i + 3 <= q) ? __expf(s[3] * 0.125f) * inv : 0.0f;
            *(float4*)(attn + ((size_t)bh * SEQ + q) * SEQ + k0i) = p4;
            uint2 pw;
            pw.x = f2bf(p4.x) | ((unsigned)f2bf(p4.y) << 16);
            pw.y = f2bf(p4.z) | ((unsigned)f2bf(p4.w) << 16);
            *(uint2*)((char*)(Psm[w]) + ((r16 * 128 + nt * 32 + g * 8) ^ ((r16 & 7) << 4))) = pw;
        }
        // PV: A = P (per-wave LDS, layout unchanged), B = V
        bf16x8 pf[2];
        #pragma unroll
        for (int k2 = 0; k2 < 2; ++k2)
            pf[k2] = *(const bf16x8*)((char*)(Psm[w]) + ((r16 * 128 + k2 * 64 + g * 16) ^ ((r16 & 7) << 4)));
        #pragma unroll
        for (int nt = 0; nt < 4; ++nt) {
            const int vrow = nt * 16 + r16;
            #pragma unroll
            for (int k2 = 0; k2 < 2; ++k2) {
                bf16x8 vf = *(const bf16x8*)(Vc + ((vrow * 128 + k2 * 64 + g * 16) ^ ((vrow & 7) << 4)));
                cacc[nt] = __builtin_amdgcn_mfma_f32_16x16x32_bf16(pf[k2], vf, cacc[nt], 0, 0, 0);
            }
        }
        if (kt < qt) {
            char* Kn = Kb + (cur ^ 1) * 8192;
            char* Vn = Vb + (cur ^ 1) * 8192;
            *(uint4*)(Kn + ((sr * 128 + sbc) ^ swz)) = a0;
            *(uint4*)(Kn + ((sr * 128 + sbc + 16) ^ swz)) = a1;
            *(uint4*)(Vn + ((sr * 128 + sbc) ^ swz)) = v0;
            *(uint4*)(Vn + ((sr * 128 + sbc + 16) ^ swz)) = v1;
        }
        __syncthreads();
    }

    // ctx write (PV layout unchanged)
    #pragma unroll
    for (int nt = 0; nt < 4; ++nt)
        #pragma unroll
        for (int rr = 0; rr < 4; ++rr) {
            const int qq = qrow0 + 4 * g + rr;
            ctx[(size_t)(b * SEQ + qq) * 1024 + h * 64 + nt * 16 + r16] = f2bf(cacc[nt][rr]);
        }

    const int colStart = 64 * (qt + 1);
    const int Wc = SEQ - colStart;
    if (Wc > 0) {
        const int w4 = Wc >> 2;
        for (int c = tid; c < 64 * w4; c += 256) {
            const int row = qt * 64 + c / w4;
            const int col = colStart + (c % w4) * 4;
            *(float4*)(attn + ((size_t)bh * SEQ + row) * SEQ + col) = make_float4(0.f, 0.f, 0.f, 0.f);
        }
    }
}

extern "C" void kernel_launch(void* const* d_in, const int* in_sizes, int n_in,
                              void* d_out, int out_size, void* d_ws, size_t ws_size,
                              hipStream_t stream)
{
    const float* x  = (const float*)d_in[0];
    const float* Wq = (const float*)d_in[1];
    const float* bq = (const float*)d_in[2];
    const float* Wk = (const float*)d_in[3];
    const float* bk = (const float*)d_in[4];
    const float* Wv = (const float*)d_in[5];
    const float* bv = (const float*)d_in[6];
    const float* Wo = (const float*)d_in[7];
    const float* bo = (const float*)d_in[8];

    float* out  = (float*)d_out;
    float* attn = out + (size_t)BATCH * SEQ * EMB;

    unsigned short* xb     = (unsigned short*)d_ws;
    unsigned short* wt_qkv = xb + (size_t)MROWS * 1024;
    unsigned short* wt_o   = wt_qkv + (size_t)3072 * 1024;
    unsigned short* qkvb   = wt_o + (size_t)1024 * 1024;
    unsigned short* vtb    = qkvb + (size_t)MROWS * 3072;
    unsigned short* ctxb   = vtb + (size_t)1024 * MROWS;

    prep_kernel<<<3072, 256, 0, stream>>>(x, Wq, Wk, Wv, Wo, xb, wt_qkv, wt_o);

    gemm_mfma_kernel<0, 24, 768><<<768, 512, 0, stream>>>(xb, wt_qkv, bq, bk, bv, qkvb, vtb);

    attn_mfma_kernel<<<1024, 256, 0, stream>>>(qkvb, vtb, attn, ctxb);

    gemm_mfma_kernel<1, 8, 256><<<256, 512, 0, stream>>>(ctxb, wt_o, bo, bo, bo, out, nullptr);
}